// Round 1
// baseline (3413.401 us; speedup 1.0000x reference)
//
#include <hip/hip_runtime.h>
#include <math.h>

// MySimpleRNN: x[B=4096,T=64,NF=128] fp32, wx[128,512], wh[512,512], b[1,512]
// out = final hidden state h[B,512] fp32 after h = tanh(x_t@wx + b + h@wh), 64 steps.
//
// Fused persistent-block design: rows of B are independent across the whole
// recurrence, so each block owns BR=16 rows, keeps h[16][512] in LDS, and
// loops t=0..63 internally. No inter-block sync, single kernel launch.
// fp32 VALU baseline (no fp32 MFMA on CDNA4). Compute floor ~1.09 ms.

#define T_STEPS 64
#define NFD     128
#define NHD     512
#define BR      16      // rows per block -> 4096/16 = 256 blocks = 1/CU
#define THREADS 256     // 4 waves -> one per SIMD

__global__ __launch_bounds__(THREADS) void rnn_fused_fp32(
    const float* __restrict__ x,
    const float* __restrict__ wx,
    const float* __restrict__ wh,
    const float* __restrict__ bias,
    float* __restrict__ out)
{
    __shared__ float sh_h[BR][NHD];   // 32 KB, current hidden state
    __shared__ float sh_x[BR][NFD];   // 8 KB, x slice for current t

    const int tid    = (int)threadIdx.x;
    const int row0_g = (int)blockIdx.x * BR;

    // compute tile: each thread owns 4 rows x 8 cols of the 16x512 output
    const int ty = tid >> 6;          // wave id 0..3 -> row group
    const int tx = tid & 63;          // 0..63       -> col group
    const int r0 = ty * 4;            // local rows r0..r0+3
    const int c0 = tx * 8;            // cols c0..c0+7 (contiguous, coalesced)

    // x staging map: 16 lanes per row, 8 floats per lane
    const int xrow = tid >> 4;        // 0..15
    const int xcol = (tid & 15) * 8;  // 0..120

    // h starts at zero
    for (int i = tid; i < BR * NHD; i += THREADS)
        ((float*)sh_h)[i] = 0.0f;

    float bias_r[8];
    #pragma unroll
    for (int j = 0; j < 8; ++j) bias_r[j] = bias[c0 + j];

    // prefetch x(t=0) into registers
    const float* xbase = x + ((row0_g + xrow) * T_STEPS) * NFD + xcol;
    float4 px0 = *(const float4*)(xbase + 0);
    float4 px1 = *(const float4*)(xbase + 4);

    for (int t = 0; t < T_STEPS; ++t) {
        // stage x(t) into LDS
        *(float4*)(&sh_x[xrow][xcol + 0]) = px0;
        *(float4*)(&sh_x[xrow][xcol + 4]) = px1;
        __syncthreads();   // sh_x(t) staged; sh_h(t) writes from t-1 visible

        // prefetch x(t+1); waitcnt lands at next iteration's LDS store,
        // fully hidden under this step's ~17us FMA stream
        if (t + 1 < T_STEPS) {
            px0 = *(const float4*)(xbase + (t + 1) * NFD + 0);
            px1 = *(const float4*)(xbase + (t + 1) * NFD + 4);
        }

        float acc[4][8];
        #pragma unroll
        for (int i = 0; i < 4; ++i)
            #pragma unroll
            for (int j = 0; j < 8; ++j)
                acc[i][j] = bias_r[j];

        // input projection: acc += x_t[r,:] @ wx[:,c]   (K = 128)
        #pragma unroll 4
        for (int k = 0; k < NFD; ++k) {
            const float a0 = sh_x[r0 + 0][k];
            const float a1 = sh_x[r0 + 1][k];
            const float a2 = sh_x[r0 + 2][k];
            const float a3 = sh_x[r0 + 3][k];
            const float4 w0 = *(const float4*)(wx + k * NHD + c0);
            const float4 w1 = *(const float4*)(wx + k * NHD + c0 + 4);
            acc[0][0] += a0 * w0.x; acc[0][1] += a0 * w0.y;
            acc[0][2] += a0 * w0.z; acc[0][3] += a0 * w0.w;
            acc[0][4] += a0 * w1.x; acc[0][5] += a0 * w1.y;
            acc[0][6] += a0 * w1.z; acc[0][7] += a0 * w1.w;
            acc[1][0] += a1 * w0.x; acc[1][1] += a1 * w0.y;
            acc[1][2] += a1 * w0.z; acc[1][3] += a1 * w0.w;
            acc[1][4] += a1 * w1.x; acc[1][5] += a1 * w1.y;
            acc[1][6] += a1 * w1.z; acc[1][7] += a1 * w1.w;
            acc[2][0] += a2 * w0.x; acc[2][1] += a2 * w0.y;
            acc[2][2] += a2 * w0.z; acc[2][3] += a2 * w0.w;
            acc[2][4] += a2 * w1.x; acc[2][5] += a2 * w1.y;
            acc[2][6] += a2 * w1.z; acc[2][7] += a2 * w1.w;
            acc[3][0] += a3 * w0.x; acc[3][1] += a3 * w0.y;
            acc[3][2] += a3 * w0.z; acc[3][3] += a3 * w0.w;
            acc[3][4] += a3 * w1.x; acc[3][5] += a3 * w1.y;
            acc[3][6] += a3 * w1.z; acc[3][7] += a3 * w1.w;
        }

        // recurrence: acc += h[r,:] @ wh[:,c]   (K = 512)
        // sh_h reads are wave-uniform per k (broadcast, conflict-free);
        // wh row reads are fully coalesced float4 across 64 lanes (2 KB/row).
        #pragma unroll 4
        for (int k = 0; k < NHD; ++k) {
            const float a0 = sh_h[r0 + 0][k];
            const float a1 = sh_h[r0 + 1][k];
            const float a2 = sh_h[r0 + 2][k];
            const float a3 = sh_h[r0 + 3][k];
            const float4 w0 = *(const float4*)(wh + k * NHD + c0);
            const float4 w1 = *(const float4*)(wh + k * NHD + c0 + 4);
            acc[0][0] += a0 * w0.x; acc[0][1] += a0 * w0.y;
            acc[0][2] += a0 * w0.z; acc[0][3] += a0 * w0.w;
            acc[0][4] += a0 * w1.x; acc[0][5] += a0 * w1.y;
            acc[0][6] += a0 * w1.z; acc[0][7] += a0 * w1.w;
            acc[1][0] += a1 * w0.x; acc[1][1] += a1 * w0.y;
            acc[1][2] += a1 * w0.z; acc[1][3] += a1 * w0.w;
            acc[1][4] += a1 * w1.x; acc[1][5] += a1 * w1.y;
            acc[1][6] += a1 * w1.z; acc[1][7] += a1 * w1.w;
            acc[2][0] += a2 * w0.x; acc[2][1] += a2 * w0.y;
            acc[2][2] += a2 * w0.z; acc[2][3] += a2 * w0.w;
            acc[2][4] += a2 * w1.x; acc[2][5] += a2 * w1.y;
            acc[2][6] += a2 * w1.z; acc[2][7] += a2 * w1.w;
            acc[3][0] += a3 * w0.x; acc[3][1] += a3 * w0.y;
            acc[3][2] += a3 * w0.z; acc[3][3] += a3 * w0.w;
            acc[3][4] += a3 * w1.x; acc[3][5] += a3 * w1.y;
            acc[3][6] += a3 * w1.z; acc[3][7] += a3 * w1.w;
        }

        __syncthreads();   // all sh_h / sh_x reads for step t complete

        if (t == T_STEPS - 1) {
            // final step: tanh straight to global (coalesced float4 x2 per row)
            #pragma unroll
            for (int i = 0; i < 4; ++i) {
                float* op = out + (row0_g + r0 + i) * NHD + c0;
                float4 o0, o1;
                o0.x = tanhf(acc[i][0]); o0.y = tanhf(acc[i][1]);
                o0.z = tanhf(acc[i][2]); o0.w = tanhf(acc[i][3]);
                o1.x = tanhf(acc[i][4]); o1.y = tanhf(acc[i][5]);
                o1.z = tanhf(acc[i][6]); o1.w = tanhf(acc[i][7]);
                *(float4*)(op + 0) = o0;
                *(float4*)(op + 4) = o1;
            }
        } else {
            #pragma unroll
            for (int i = 0; i < 4; ++i) {
                float4 h0, h1;
                h0.x = tanhf(acc[i][0]); h0.y = tanhf(acc[i][1]);
                h0.z = tanhf(acc[i][2]); h0.w = tanhf(acc[i][3]);
                h1.x = tanhf(acc[i][4]); h1.y = tanhf(acc[i][5]);
                h1.z = tanhf(acc[i][6]); h1.w = tanhf(acc[i][7]);
                *(float4*)(&sh_h[r0 + i][c0 + 0]) = h0;
                *(float4*)(&sh_h[r0 + i][c0 + 4]) = h1;
            }
        }
    }
}

extern "C" void kernel_launch(void* const* d_in, const int* in_sizes, int n_in,
                              void* d_out, int out_size, void* d_ws, size_t ws_size,
                              hipStream_t stream) {
    const float* x    = (const float*)d_in[0];  // [B, 64, 128]
    const float* wx   = (const float*)d_in[1];  // [128, 512]
    const float* wh   = (const float*)d_in[2];  // [512, 512]
    const float* bias = (const float*)d_in[3];  // [512]
    float* out = (float*)d_out;                 // [B, 512]

    const int B = in_sizes[0] / (T_STEPS * NFD);   // 4096
    const int grid = B / BR;                        // 256 blocks

    rnn_fused_fp32<<<grid, THREADS, 0, stream>>>(x, wx, wh, bias, out);
}

// Round 2
// 1098.328 us; speedup vs baseline: 3.1078x; 3.1078x over previous
//
#include <hip/hip_runtime.h>
#include <math.h>

// MySimpleRNN on MI355X — fp16 hi/lo split MFMA version.
// h = tanh(x_t@wx + b + h@wh), 64 steps, B=4096, NF=128, NH=512.
// Each block owns 16 rows of B; h kept in LDS as fp16 hi+lo; weights
// pre-split into fp16 hi/lo and pre-packed into MFMA B-fragment-linear
// layout in d_ws. 3 MFMA products (hi*hi + lo*hi + hi*lo) per matmul
// give ~fp32-level per-step noise (residual ~2^-24).
//
// mfma_f32_16x16x32_f16 layouts (verified in learn_hip m89/m91/m120):
//   A: lane holds A[m=lane&15][k=(lane>>4)*8+j], j=0..7
//   B: lane holds B[k=(lane>>4)*8+j][n=lane&15]
//   C/D: reg r holds C[row=(lane>>4)*4+r][col=lane&15]

#define T_STEPS 64
#define NFD     128
#define NHD     512
#define BR      16
#define THREADS 512          // 8 waves, 2 per SIMD
#define LDH     (NHD + 8)    // padded fp16 row: stride 1040 B (16B-aligned, banks offset 4/row)
#define LDX     (NFD + 8)    // stride 272 B

typedef _Float16 half8 __attribute__((ext_vector_type(8)));
typedef _Float16 half4v __attribute__((ext_vector_type(4)));
typedef float float4v __attribute__((ext_vector_type(4)));

// ---- prep: split wh/wx into fp16 hi/lo and pack into fragment-linear layout ----
// whp index: ((nt*16 + kb)*64 + lane)*8 + j  <- wh[(kb*32 + (lane>>4)*8 + j)*512 + nt*16 + (lane&15)]
// wxp index: ((nt*4  + kb)*64 + lane)*8 + j  <- wx[(kb*32 + (lane>>4)*8 + j)*512 + nt*16 + (lane&15)]
__global__ __launch_bounds__(256) void rnn_prep(
    const float* __restrict__ wh, const float* __restrict__ wx,
    _Float16* __restrict__ whp_hi, _Float16* __restrict__ whp_lo,
    _Float16* __restrict__ wxp_hi, _Float16* __restrict__ wxp_lo)
{
    int idx = blockIdx.x * 256 + threadIdx.x;   // grid covers 262144
    {
        int j  = idx & 7;
        int l  = (idx >> 3) & 63;
        int kb = (idx >> 9) & 15;
        int nt = idx >> 13;                     // 0..31
        int k  = kb * 32 + (l >> 4) * 8 + j;
        int n  = nt * 16 + (l & 15);
        float v = wh[k * NHD + n];
        _Float16 hi = (_Float16)v;
        whp_hi[idx] = hi;
        whp_lo[idx] = (_Float16)(v - (float)hi);
    }
    if (idx < 65536) {
        int j  = idx & 7;
        int l  = (idx >> 3) & 63;
        int kb = (idx >> 9) & 3;
        int nt = idx >> 11;                     // 0..31
        int k  = kb * 32 + (l >> 4) * 8 + j;
        int n  = nt * 16 + (l & 15);
        float v = wx[k * NHD + n];
        _Float16 hi = (_Float16)v;
        wxp_hi[idx] = hi;
        wxp_lo[idx] = (_Float16)(v - (float)hi);
    }
}

// ---- main fused recurrence ----
__global__ __launch_bounds__(THREADS) void rnn_mfma(
    const float* __restrict__ x,
    const float* __restrict__ bias,
    const _Float16* __restrict__ whp_hi, const _Float16* __restrict__ whp_lo,
    const _Float16* __restrict__ wxp_hi, const _Float16* __restrict__ wxp_lo,
    float* __restrict__ out)
{
    __shared__ _Float16 sh_hhi[BR * LDH];
    __shared__ _Float16 sh_hlo[BR * LDH];
    __shared__ _Float16 sh_xhi[BR * LDX];
    __shared__ _Float16 sh_xlo[BR * LDX];

    const int tid  = (int)threadIdx.x;
    const int lane = tid & 63;
    const int w    = tid >> 6;        // wave 0..7, owns cols [w*64, w*64+64)
    const int m    = lane & 15;       // A-row / C-col lane index
    const int quad = lane >> 4;
    const int row0 = (int)blockIdx.x * BR;

    // zero h
    for (int i = tid; i < BR * LDH; i += THREADS) {
        sh_hhi[i] = (_Float16)0.f;
        sh_hlo[i] = (_Float16)0.f;
    }

    // bias for this lane's 4 col-tiles
    float bv[4];
    #pragma unroll
    for (int nt = 0; nt < 4; ++nt) bv[nt] = bias[w * 64 + nt * 16 + m];

    // x prefetch: 512 threads cover 16 rows x 128 floats, 4 floats each
    const int xrow = tid >> 5;         // 0..15
    const int xcol = (tid & 31) * 4;   // 0..124
    const float* xptr = x + (row0 + xrow) * (T_STEPS * NFD) + xcol;
    float4 px = *(const float4*)xptr;

    const half8* whh = (const half8*)whp_hi;
    const half8* whl = (const half8*)whp_lo;
    const half8* wxh = (const half8*)wxp_hi;
    const half8* wxl = (const half8*)wxp_lo;

    for (int t = 0; t < T_STEPS; ++t) {
        // stage x(t): split fp32 -> hi/lo fp16
        {
            half4v vh, vl;
            float xs[4] = {px.x, px.y, px.z, px.w};
            #pragma unroll
            for (int j = 0; j < 4; ++j) {
                _Float16 hi = (_Float16)xs[j];
                vh[j] = hi;
                vl[j] = (_Float16)(xs[j] - (float)hi);
            }
            *(half4v*)&sh_xhi[xrow * LDX + xcol] = vh;
            *(half4v*)&sh_xlo[xrow * LDX + xcol] = vl;
        }
        __syncthreads();   // x staged + h(t-1) writes visible

        if (t + 1 < T_STEPS) px = *(const float4*)(xptr + (t + 1) * NFD);

        float4v acc[4];
        #pragma unroll
        for (int nt = 0; nt < 4; ++nt) {
            acc[nt][0] = bv[nt]; acc[nt][1] = bv[nt];
            acc[nt][2] = bv[nt]; acc[nt][3] = bv[nt];
        }

        // input projection: K = 128 -> 4 k-blocks of 32
        #pragma unroll
        for (int kb = 0; kb < 4; ++kb) {
            half8 ahi = *(const half8*)&sh_xhi[m * LDX + kb * 32 + quad * 8];
            half8 alo = *(const half8*)&sh_xlo[m * LDX + kb * 32 + quad * 8];
            half8 bh[4], bl[4];
            #pragma unroll
            for (int nt = 0; nt < 4; ++nt) {
                int fi = ((w * 4 + nt) * 4 + kb) * 64 + lane;
                bh[nt] = wxh[fi];
                bl[nt] = wxl[fi];
            }
            #pragma unroll
            for (int nt = 0; nt < 4; ++nt) {
                acc[nt] = __builtin_amdgcn_mfma_f32_16x16x32_f16(ahi, bh[nt], acc[nt], 0, 0, 0);
                acc[nt] = __builtin_amdgcn_mfma_f32_16x16x32_f16(alo, bh[nt], acc[nt], 0, 0, 0);
                acc[nt] = __builtin_amdgcn_mfma_f32_16x16x32_f16(ahi, bl[nt], acc[nt], 0, 0, 0);
            }
        }

        // recurrence: K = 512 -> 16 k-blocks of 32
        #pragma unroll 4
        for (int kb = 0; kb < 16; ++kb) {
            half8 ahi = *(const half8*)&sh_hhi[m * LDH + kb * 32 + quad * 8];
            half8 alo = *(const half8*)&sh_hlo[m * LDH + kb * 32 + quad * 8];
            half8 bh[4], bl[4];
            #pragma unroll
            for (int nt = 0; nt < 4; ++nt) {
                int fi = ((w * 4 + nt) * 16 + kb) * 64 + lane;
                bh[nt] = whh[fi];
                bl[nt] = whl[fi];
            }
            #pragma unroll
            for (int nt = 0; nt < 4; ++nt) {
                acc[nt] = __builtin_amdgcn_mfma_f32_16x16x32_f16(ahi, bh[nt], acc[nt], 0, 0, 0);
                acc[nt] = __builtin_amdgcn_mfma_f32_16x16x32_f16(alo, bh[nt], acc[nt], 0, 0, 0);
                acc[nt] = __builtin_amdgcn_mfma_f32_16x16x32_f16(ahi, bl[nt], acc[nt], 0, 0, 0);
            }
        }

        __syncthreads();   // all h/x reads for step t done

        // epilogue: tanh, split, write back (C/D layout: row=quad*4+r, col=w*64+nt*16+m)
        if (t == T_STEPS - 1) {
            #pragma unroll
            for (int nt = 0; nt < 4; ++nt)
                #pragma unroll
                for (int r = 0; r < 4; ++r)
                    out[(row0 + quad * 4 + r) * NHD + w * 64 + nt * 16 + m] = tanhf(acc[nt][r]);
        } else {
            #pragma unroll
            for (int nt = 0; nt < 4; ++nt) {
                #pragma unroll
                for (int r = 0; r < 4; ++r) {
                    float v = tanhf(acc[nt][r]);
                    _Float16 hi = (_Float16)v;
                    int off = (quad * 4 + r) * LDH + w * 64 + nt * 16 + m;
                    sh_hhi[off] = hi;
                    sh_hlo[off] = (_Float16)(v - (float)hi);
                }
            }
        }
    }
}

extern "C" void kernel_launch(void* const* d_in, const int* in_sizes, int n_in,
                              void* d_out, int out_size, void* d_ws, size_t ws_size,
                              hipStream_t stream) {
    const float* x    = (const float*)d_in[0];  // [B, 64, 128]
    const float* wx   = (const float*)d_in[1];  // [128, 512]
    const float* wh   = (const float*)d_in[2];  // [512, 512]
    const float* bias = (const float*)d_in[3];  // [512]
    float* out = (float*)d_out;                 // [B, 512]

    // workspace layout (fp16): whp_hi 512KB | whp_lo 512KB | wxp_hi 128KB | wxp_lo 128KB
    char* ws = (char*)d_ws;
    _Float16* whp_hi = (_Float16*)(ws);
    _Float16* whp_lo = (_Float16*)(ws + 524288);
    _Float16* wxp_hi = (_Float16*)(ws + 1048576);
    _Float16* wxp_lo = (_Float16*)(ws + 1048576 + 131072);

    rnn_prep<<<1024, 256, 0, stream>>>(wh, wx, whp_hi, whp_lo, wxp_hi, wxp_lo);

    const int B = in_sizes[0] / (T_STEPS * NFD);   // 4096
    rnn_mfma<<<B / BR, THREADS, 0, stream>>>(x, bias, whp_hi, whp_lo, wxp_hi, wxp_lo, out);
}